// Round 1
// baseline (262.983 us; speedup 1.0000x reference)
//
#include <hip/hip_runtime.h>
#include <hip/hip_bf16.h>
#include <stdint.h>

typedef __attribute__((ext_vector_type(8))) short short8;
typedef __attribute__((ext_vector_type(4))) float f32x4;

#define NBATCH 4096
#define NNODE  17
#define NDIM   512
#define ROWLEN 8704   // 17*512

__device__ __forceinline__ unsigned short f2bf(float f) {
    union { float f; unsigned int u; } v; v.f = f;
    unsigned int r = v.u + 0x7fffu + ((v.u >> 16) & 1u);   // round-nearest-even
    return (unsigned short)(r >> 16);
}
__device__ __forceinline__ unsigned int pk2(unsigned short a, unsigned short b) {
    return (unsigned int)a | ((unsigned int)b << 16);
}
__device__ __forceinline__ float silu_f(float x) {
    return x / (1.0f + __expf(-x));
}

// ---------------------------------------------------------------------------
// Kernel 1: blocks [0,128)  : transpose-cast W_mod [512][1024] f32 -> wbT [1024][512] bf16
//           blocks [128,1152): cb[b][c] = bf16(silu(c_in[b][c]))   (4096*512 elems, 8/thread)
// ---------------------------------------------------------------------------
__global__ __launch_bounds__(256) void prep_kernel(
        const float* __restrict__ cin, const float* __restrict__ Wmod,
        unsigned short* __restrict__ cb, unsigned short* __restrict__ wbT) {
    int bid = blockIdx.x;
    int tid = threadIdx.x;
    if (bid < 128) {
        __shared__ float tile[64][65];
        int txt = bid & 15, tyt = bid >> 4;      // col-tile (1024/64), row-tile (512/64)
        int cx = tid & 63, ry = tid >> 6;
        #pragma unroll
        for (int rr = 0; rr < 16; ++rr) {
            int r = ry + rr * 4;
            tile[r][cx] = Wmod[(tyt*64 + r) * 1024 + txt*64 + cx];
        }
        __syncthreads();
        #pragma unroll
        for (int rr = 0; rr < 16; ++rr) {
            int r = ry + rr * 4;
            wbT[(txt*64 + r) * 512 + tyt*64 + cx] = f2bf(tile[cx][r]);
        }
    } else {
        int t = (bid - 128) * 256 + tid;          // < 262144, 8 elems each
        const float4* s = reinterpret_cast<const float4*>(cin) + (size_t)t * 2;
        float4 a = s[0], b = s[1];
        uint4 o;
        o.x = pk2(f2bf(silu_f(a.x)), f2bf(silu_f(a.y)));
        o.y = pk2(f2bf(silu_f(a.z)), f2bf(silu_f(a.w)));
        o.z = pk2(f2bf(silu_f(b.x)), f2bf(silu_f(b.y)));
        o.w = pk2(f2bf(silu_f(b.z)), f2bf(silu_f(b.w)));
        *reinterpret_cast<uint4*>(cb + (size_t)t * 8) = o;
    }
}

// ---------------------------------------------------------------------------
// Kernel 2: H[4096][1024] = cb[4096][512] @ wbT^T + b_mod   (MFMA bf16)
// block = 4 waves, each wave: 32 rows x 64 cols (2x4 fragments). grid (16, 32).
// ---------------------------------------------------------------------------
__global__ __launch_bounds__(256) void gemm_kernel(
        const unsigned short* __restrict__ cb, const unsigned short* __restrict__ wbT,
        const float* __restrict__ b_mod, float* __restrict__ H) {
    int w = threadIdx.x >> 6, l = threadIdx.x & 63;
    int lr = l & 15, lk = (l >> 4) * 8;
    int rowbase = blockIdx.y * 128 + w * 32;
    int colbase = blockIdx.x * 64;
    f32x4 acc[2][4] = {};
    for (int kk = 0; kk < 16; ++kk) {
        int k = kk * 32 + lk;
        short8 a0 = *reinterpret_cast<const short8*>(cb + (size_t)(rowbase + lr) * 512 + k);
        short8 a1 = *reinterpret_cast<const short8*>(cb + (size_t)(rowbase + 16 + lr) * 512 + k);
        #pragma unroll
        for (int j = 0; j < 4; ++j) {
            short8 bv = *reinterpret_cast<const short8*>(wbT + (size_t)(colbase + j*16 + lr) * 512 + k);
            acc[0][j] = __builtin_amdgcn_mfma_f32_16x16x32_bf16(a0, bv, acc[0][j], 0, 0, 0);
            acc[1][j] = __builtin_amdgcn_mfma_f32_16x16x32_bf16(a1, bv, acc[1][j], 0, 0, 0);
        }
    }
    #pragma unroll
    for (int j = 0; j < 4; ++j) {
        int col = colbase + j * 16 + lr;
        float bm = b_mod[col];
        #pragma unroll
        for (int i = 0; i < 2; ++i) {
            int row0 = rowbase + i * 16 + (l >> 4) * 4;
            #pragma unroll
            for (int r = 0; r < 4; ++r)
                H[(size_t)(row0 + r) * 1024 + col] = acc[i][j][r] + bm;
        }
    }
}

// ---------------------------------------------------------------------------
// Kernel 3: fused LayerNorm + modulate + Cheb projection + graph combine.
// One block (512 thr, 8 waves) per batch element.
//   A = bf16(xn) [17(pad32) x 512], B = bf16((1+scale)*Wg) [9(pad16) x 512 col-major]
//   P = A@B^T via 32 MFMA; shift@Wg computed exactly in f32 (rank-1 term);
//   out = (P0-P2) + L*P1 + 2L*(L*P2)
// ---------------------------------------------------------------------------
__global__ __launch_bounds__(512) void main_kernel(
        const float* __restrict__ x, const float* __restrict__ adj,
        const float* __restrict__ Wg, const float* __restrict__ bg,
        const float* __restrict__ H, float* __restrict__ out) {
    __shared__ __align__(16) unsigned short xm_lds[32][520];   // bf16 xn, rows 17..31 unused
    __shared__ __align__(16) unsigned short wg_lds[16][520];   // bf16 (1+sc)*Wg, rows 9..15 unused
    __shared__ float L_lds[17][18];
    __shared__ float P_lds[32][16];
    __shared__ float Q_lds[17][4];
    __shared__ float S_lds[12];

    int b = blockIdx.x;
    int tid = threadIdx.x;
    int w = tid >> 6, l = tid & 63;

    if (w == 7) {
        // fold (1 + scale) into Wg:  wg_lds[k*3+o][c] = bf16((1+sc_c)*Wg[k][c][o])
        for (int c = l; c < 512; c += 64) {
            float f = 1.0f + H[(size_t)b * 1024 + 512 + c];
            #pragma unroll
            for (int k = 0; k < 3; ++k)
                #pragma unroll
                for (int o = 0; o < 3; ++o)
                    wg_lds[k*3 + o][c] = f2bf(f * Wg[k*1536 + c*3 + o]);
        }
    } else if (w == 6) {
        // normalized Laplacian L = I - d A d
        float dv = 0.0f;
        if (l < 17) {
            float rs = 0.0f;
            #pragma unroll
            for (int j = 0; j < 17; ++j) rs += adj[l*17 + j];
            dv = rsqrtf(rs);
        }
        for (int e = l; e < 289; e += 64) {
            int i = e / 17, j = e - i * 17;
            float di = __shfl(dv, i), dj = __shfl(dv, j);
            L_lds[i][j] = (i == j ? 1.0f : 0.0f) - di * adj[e] * dj;
        }
    } else if (w == 2) {
        // exact f32 shift-projection: S[k*3+o] = sum_c shift_c * Wg[k][c][o]
        float p0=0,p1=0,p2=0,p3=0,p4=0,p5=0,p6=0,p7=0,p8=0;
        for (int c = l; c < 512; c += 64) {
            float shv = H[(size_t)b * 1024 + c];
            const float* wr = Wg + c * 3;
            p0 += shv * wr[0];      p1 += shv * wr[1];      p2 += shv * wr[2];
            p3 += shv * wr[1536];   p4 += shv * wr[1537];   p5 += shv * wr[1538];
            p6 += shv * wr[3072];   p7 += shv * wr[3073];   p8 += shv * wr[3074];
        }
        #pragma unroll
        for (int m = 1; m < 64; m <<= 1) {
            p0 += __shfl_xor(p0, m); p1 += __shfl_xor(p1, m); p2 += __shfl_xor(p2, m);
            p3 += __shfl_xor(p3, m); p4 += __shfl_xor(p4, m); p5 += __shfl_xor(p5, m);
            p6 += __shfl_xor(p6, m); p7 += __shfl_xor(p7, m); p8 += __shfl_xor(p8, m);
        }
        if (l == 0) {
            S_lds[0]=p0; S_lds[1]=p1; S_lds[2]=p2; S_lds[3]=p3; S_lds[4]=p4;
            S_lds[5]=p5; S_lds[6]=p6; S_lds[7]=p7; S_lds[8]=p8;
        }
    }

    // all 8 waves: per-node LayerNorm; x read exactly once from HBM
    const float* xb = x + (size_t)b * ROWLEN;
    for (int n = w; n < 17; n += 8) {
        const float4* xp = reinterpret_cast<const float4*>(xb + n * 512 + 8 * l);
        float4 v0 = xp[0], v1 = xp[1];
        float xv[8] = {v0.x, v0.y, v0.z, v0.w, v1.x, v1.y, v1.z, v1.w};
        float s = 0.0f, s2 = 0.0f;
        #pragma unroll
        for (int j = 0; j < 8; ++j) { s += xv[j]; s2 += xv[j] * xv[j]; }
        #pragma unroll
        for (int m = 1; m < 64; m <<= 1) { s += __shfl_xor(s, m); s2 += __shfl_xor(s2, m); }
        float mu = s * (1.0f / 512.0f);
        float var = s2 * (1.0f / 512.0f) - mu * mu;
        float rstd = rsqrtf(var + 1e-6f);
        unsigned short hv[8];
        #pragma unroll
        for (int j = 0; j < 8; ++j) hv[j] = f2bf((xv[j] - mu) * rstd);
        uint4 ov;
        ov.x = pk2(hv[0], hv[1]); ov.y = pk2(hv[2], hv[3]);
        ov.z = pk2(hv[4], hv[5]); ov.w = pk2(hv[6], hv[7]);
        *reinterpret_cast<uint4*>(&xm_lds[n][8 * l]) = ov;
    }
    __syncthreads();

    // waves 0,1: P = xn @ ((1+sc)*Wg)  via MFMA (wave w covers rows 16w..16w+15)
    if (w < 2) {
        int lr = l & 15, lk = (l >> 4) * 8;
        f32x4 acc = {0.f, 0.f, 0.f, 0.f};
        #pragma unroll
        for (int kk = 0; kk < 16; ++kk) {
            int k = kk * 32 + lk;
            short8 av = *reinterpret_cast<const short8*>(&xm_lds[w * 16 + lr][k]);
            short8 bv = *reinterpret_cast<const short8*>(&wg_lds[lr][k]);
            acc = __builtin_amdgcn_mfma_f32_16x16x32_bf16(av, bv, acc, 0, 0, 0);
        }
        int pr = w * 16 + (l >> 4) * 4;
        #pragma unroll
        for (int r = 0; r < 4; ++r) P_lds[pr + r][lr] = acc[r];
    }
    __syncthreads();

    if (tid < 153) {                       // P += shift-projection (rows 0..16, cols 0..8)
        int n = tid / 9, r = tid - n * 9;
        P_lds[n][r] += S_lds[r];
    }
    __syncthreads();

    if (tid < 51) {                        // Q = L * P2
        int n = tid / 3, o = tid - n * 3;
        float q = 0.0f;
        #pragma unroll
        for (int m = 0; m < 17; ++m) q += L_lds[n][m] * P_lds[m][6 + o];
        Q_lds[n][o] = q;
    }
    __syncthreads();

    if (tid < 51) {                        // out = (P0 - P2) + L*(P1 + 2Q) + bg
        int n = tid / 3, o = tid - n * 3;
        float r = P_lds[n][o] - P_lds[n][6 + o] + bg[o];
        #pragma unroll
        for (int m = 0; m < 17; ++m)
            r += L_lds[n][m] * (P_lds[m][3 + o] + 2.0f * Q_lds[m][o]);
        out[(size_t)b * 51 + tid] = r;
    }
}

// ---------------------------------------------------------------------------
extern "C" void kernel_launch(void* const* d_in, const int* in_sizes, int n_in,
                              void* d_out, int out_size, void* d_ws, size_t ws_size,
                              hipStream_t stream) {
    const float* x     = (const float*)d_in[0];
    const float* adj   = (const float*)d_in[1];
    const float* c     = (const float*)d_in[2];
    const float* W_mod = (const float*)d_in[3];
    const float* b_mod = (const float*)d_in[4];
    const float* Wg    = (const float*)d_in[5];
    const float* bg    = (const float*)d_in[6];
    float* out = (float*)d_out;

    // workspace layout: cb 4MB @0 | wbT 1MB @4MB | H 16MB @5MB  (21MB total)
    unsigned short* cb  = (unsigned short*)d_ws;
    unsigned short* wbT = (unsigned short*)((char*)d_ws + (4u << 20));
    float*          H   = (float*)((char*)d_ws + (5u << 20));

    prep_kernel<<<1152, 256, 0, stream>>>(c, W_mod, cb, wbT);
    gemm_kernel<<<dim3(16, 32), 256, 0, stream>>>(cb, wbT, b_mod, H);
    main_kernel<<<4096, 512, 0, stream>>>(x, adj, Wg, bg, H, out);
}